// Round 1
// baseline (1303.503 us; speedup 1.0000x reference)
//
#include <hip/hip_runtime.h>
#include <cmath>

// ---------------------------------------------------------------------------
// Performer (FAVOR+) attention, fp32, MI355X.
// Algebra: ratio cancels; k-side stabilizer S applied post-hoc (exp range safe);
// q-side rowmax applied post-hoc. See derivation in session notes.
//   qph = exp(qd - diag_q)                (unstabilized)
//   U[m][e] = sum_n exp(kd - diag_k) v ;  u[m] = sum_n exp(kd - diag_k)
//   ctx'[m][e] = (e^-S U + eps sv[e]) / L ; kmean'[m] = e^-S u / L + eps
//   out = (A + eps e^{rm} Sc) / (B + eps e^{rm} Sk),
//     A = qph . ctx', B = qph . kmean', Sc = sum_m ctx', Sk = sum_m kmean'
// ---------------------------------------------------------------------------

namespace {
constexpr float NORM       = 0.35355339059327379f; // 64^-0.25
constexpr float DIAG_SCALE = 0.0625f;              // 0.5 * 64^-0.5
constexpr float EPSV       = 1e-4f;
constexpr float INV_L      = 1.0f / 4096.0f;

// workspace layout (float offsets)
constexpr size_t OFF_PT  = 0;                          // PT[64][272] (normalized, zero-padded m>=266)
constexpr size_t OFF_U   = OFF_PT + (size_t)64 * 272;  // U[32][272][64]
constexpr size_t OFF_u   = OFF_U + (size_t)32 * 272 * 64; // u[32][272]
constexpr size_t OFF_SV  = OFF_u + (size_t)32 * 272;   // sv[32][64]
constexpr size_t OFF_SC  = OFF_SV + (size_t)32 * 64;   // Sc[32][64]
constexpr size_t OFF_SK  = OFF_SC + (size_t)32 * 64;   // Sk[32]
constexpr size_t OFF_S   = OFF_SK + 32;                // S (1, encoded uint)
constexpr size_t OFF_CTX = OFF_S + 4;                  // ctx_ext[32][272][68] (col64=kmean', 65..67=0)
constexpr size_t WS_FLOATS = OFF_CTX + (size_t)32 * 272 * 68;
} // namespace

__device__ __forceinline__ unsigned fenc(float f) {
  unsigned u = __float_as_uint(f);
  return (u & 0x80000000u) ? ~u : (u | 0x80000000u);
}
__device__ __forceinline__ float fdec(unsigned u) {
  return (u & 0x80000000u) ? __uint_as_float(u ^ 0x80000000u) : __uint_as_float(~u);
}

// --------------------------- K0: setup -------------------------------------
__global__ __launch_bounds__(256) void setup_kernel(const float* __restrict__ P,
                                                    float* __restrict__ ws) {
  const int t = threadIdx.x;
  const int elem = blockIdx.x * 256 + t; // < 64*272 exactly (grid 68)
  const int td = elem / 272, mm = elem % 272;
  ws[OFF_PT + (size_t)td * 272 + mm] = (mm < 266) ? NORM * P[mm * 64 + td] : 0.0f;
  if (blockIdx.x == 0 && t == 0) ((unsigned*)(ws + OFF_S))[0] = 0x007FFFFFu; // enc(-inf)
}

// --------------------------- K1: k-pass main (m in [0,256)) -----------------
__global__ __launch_bounds__(256) void pass_k_main(const float* __restrict__ kg,
                                                   const float* __restrict__ vg,
                                                   float* __restrict__ ws) {
  __shared__ __align__(16) float kT[64 * 68]; // kT[td][row], stride 68
  __shared__ __align__(16) float vS[64 * 68]; // vS[row][e],  stride 68
  __shared__ __align__(16) float kp[64 * 68]; // kp[row][m_local], stride 68
  __shared__ float diag[64];
  __shared__ float redb[4];

  const int t = threadIdx.x;
  const int mb = blockIdx.x, bh = blockIdx.y, ns = blockIdx.z;
  const int lane = t & 63, wv = t >> 6;
  const int mq = t & 15, rg = t >> 4;          // GEMM1: 16 m-quads x 16 row-groups(4)
  const int mo = t & 7, eo = (t >> 3) & 7;     // GEMM2: 8 m-octs x 8 e-octs
  const int rs = t >> 6;                       // GEMM2: n quarter (= wave id)

  float acc2[8][8];
#pragma unroll
  for (int i = 0; i < 8; ++i)
#pragma unroll
    for (int j = 0; j < 8; ++j) acc2[i][j] = 0.f;
  float uacc[8] = {0, 0, 0, 0, 0, 0, 0, 0};
  float smax = -INFINITY;

  const size_t base = ((size_t)bh * 4096 + (size_t)ns * 1024) * 64;
  const float* ptp = ws + OFF_PT + mb * 64 + mq * 4;

  for (int sc = 0; sc < 16; ++sc) {
    const float* kgp = kg + base + (size_t)sc * 64 * 64;
    const float* vgp = vg + base + (size_t)sc * 64 * 64;
    __syncthreads(); // previous iter's LDS reads complete
#pragma unroll
    for (int i = 0; i < 16; ++i) {
      const int row = i * 4 + wv;
      const float kv = kgp[row * 64 + lane];
      kT[lane * 68 + row] = kv;
      vS[row * 68 + lane] = vgp[row * 64 + lane];
      float sq = kv * kv;
#pragma unroll
      for (int o = 32; o > 0; o >>= 1) sq += __shfl_xor(sq, o);
      if (lane == 0) diag[row] = sq * DIAG_SCALE;
    }
    __syncthreads();
    // GEMM1: kd[rows 4][m 4]
    float a1[4][4];
#pragma unroll
    for (int i = 0; i < 4; ++i) { a1[i][0] = a1[i][1] = a1[i][2] = a1[i][3] = 0.f; }
#pragma unroll 4
    for (int td = 0; td < 64; ++td) {
      const float4 kr4 = *(const float4*)(kT + td * 68 + rg * 4);
      const float4 pr4 = *(const float4*)(ptp + (size_t)td * 272);
      const float kk[4] = {kr4.x, kr4.y, kr4.z, kr4.w};
      const float pp[4] = {pr4.x, pr4.y, pr4.z, pr4.w};
#pragma unroll
      for (int i = 0; i < 4; ++i)
#pragma unroll
        for (int j = 0; j < 4; ++j) a1[i][j] = fmaf(kk[i], pp[j], a1[i][j]);
    }
    // exp + store kp, track raw-kd max
#pragma unroll
    for (int i = 0; i < 4; ++i) {
      const int row = rg * 4 + i;
      const float dg = diag[row];
      smax = fmaxf(smax, fmaxf(fmaxf(a1[i][0], a1[i][1]), fmaxf(a1[i][2], a1[i][3])));
      float4 st;
      st.x = __expf(a1[i][0] - dg);
      st.y = __expf(a1[i][1] - dg);
      st.z = __expf(a1[i][2] - dg);
      st.w = __expf(a1[i][3] - dg);
      *(float4*)(kp + row * 68 + mq * 4) = st;
    }
    __syncthreads();
    // GEMM2: U_partial[8m][8e] += kp^T * v over this sub-chunk (n split by wave)
#pragma unroll 2
    for (int nn = 0; nn < 16; ++nn) {
      const int n = rs * 16 + nn;
      const float4 ka = *(const float4*)(kp + n * 68 + mo * 8);
      const float4 kb = *(const float4*)(kp + n * 68 + mo * 8 + 4);
      const float4 va = *(const float4*)(vS + n * 68 + eo * 8);
      const float4 vb = *(const float4*)(vS + n * 68 + eo * 8 + 4);
      const float kk[8] = {ka.x, ka.y, ka.z, ka.w, kb.x, kb.y, kb.z, kb.w};
      const float vv[8] = {va.x, va.y, va.z, va.w, vb.x, vb.y, vb.z, vb.w};
#pragma unroll
      for (int i = 0; i < 8; ++i)
#pragma unroll
        for (int j = 0; j < 8; ++j) acc2[i][j] = fmaf(kk[i], vv[j], acc2[i][j]);
      if (eo == 0) {
#pragma unroll
        for (int i = 0; i < 8; ++i) uacc[i] += kk[i];
      }
    }
  }
  // writeback
  {
    float* Ub = ws + OFF_U + ((size_t)bh * 272 + mb * 64 + mo * 8) * 64 + eo * 8;
#pragma unroll
    for (int i = 0; i < 8; ++i)
#pragma unroll
      for (int j = 0; j < 8; ++j) atomicAdd(Ub + (size_t)i * 64 + j, acc2[i][j]);
    if (eo == 0) {
#pragma unroll
      for (int i = 0; i < 8; ++i)
        atomicAdd(ws + OFF_u + (size_t)bh * 272 + mb * 64 + mo * 8 + i, uacc[i]);
    }
  }
#pragma unroll
  for (int o = 32; o > 0; o >>= 1) smax = fmaxf(smax, __shfl_xor(smax, o));
  if (lane == 0) redb[wv] = smax;
  __syncthreads();
  if (t == 0) {
    const float m = fmaxf(fmaxf(redb[0], redb[1]), fmaxf(redb[2], redb[3]));
    atomicMax((unsigned*)(ws + OFF_S), fenc(m));
  }
}

// --------------------------- K1b: k-pass tail (m in [256,266)) --------------
__global__ __launch_bounds__(256) void pass_k_tail(const float* __restrict__ kg,
                                                   const float* __restrict__ vg,
                                                   float* __restrict__ ws) {
  __shared__ __align__(16) float kT[64 * 68];
  __shared__ __align__(16) float vS[64 * 68];
  __shared__ __align__(16) float kp[64 * 20]; // kp[row][m_local 16], stride 20
  __shared__ float diag[64];
  __shared__ float redb[4];

  const int t = threadIdx.x;
  const int bh = blockIdx.x, ns = blockIdx.y;
  const int lane = t & 63, wv = t >> 6;
  const int m4 = t & 3, rg1 = t >> 2;          // GEMM1: 1 row, 4 m's
  const int eg = (t >> 2) & 15, rs = t >> 6;   // GEMM2: 4m x 4e x 4 n-quarters

  float acc2[4][4];
#pragma unroll
  for (int i = 0; i < 4; ++i) { acc2[i][0] = acc2[i][1] = acc2[i][2] = acc2[i][3] = 0.f; }
  float uacc[4] = {0, 0, 0, 0};
  float smax = -INFINITY;

  const size_t base = ((size_t)bh * 4096 + (size_t)ns * 1024) * 64;

  for (int sc = 0; sc < 16; ++sc) {
    const float* kgp = kg + base + (size_t)sc * 64 * 64;
    const float* vgp = vg + base + (size_t)sc * 64 * 64;
    __syncthreads();
#pragma unroll
    for (int i = 0; i < 16; ++i) {
      const int row = i * 4 + wv;
      const float kv = kgp[row * 64 + lane];
      kT[lane * 68 + row] = kv;
      vS[row * 68 + lane] = vgp[row * 64 + lane];
      float sq = kv * kv;
#pragma unroll
      for (int o = 32; o > 0; o >>= 1) sq += __shfl_xor(sq, o);
      if (lane == 0) diag[row] = sq * DIAG_SCALE;
    }
    __syncthreads();
    float a1[4] = {0, 0, 0, 0};
#pragma unroll 4
    for (int td = 0; td < 64; ++td) {
      const float kv = kT[td * 68 + rg1];
      const float4 pr4 = *(const float4*)(ws + OFF_PT + (size_t)td * 272 + 256 + m4 * 4);
      a1[0] = fmaf(kv, pr4.x, a1[0]);
      a1[1] = fmaf(kv, pr4.y, a1[1]);
      a1[2] = fmaf(kv, pr4.z, a1[2]);
      a1[3] = fmaf(kv, pr4.w, a1[3]);
    }
    {
      const float dg = diag[rg1];
      float4 st;
      float vals[4];
#pragma unroll
      for (int j = 0; j < 4; ++j) {
        const int m = 256 + m4 * 4 + j;
        float e = 0.f;
        if (m < 266) {
          smax = fmaxf(smax, a1[j]);
          e = __expf(a1[j] - dg);
        }
        vals[j] = e;
      }
      st.x = vals[0]; st.y = vals[1]; st.z = vals[2]; st.w = vals[3];
      *(float4*)(kp + rg1 * 20 + m4 * 4) = st;
    }
    __syncthreads();
#pragma unroll 2
    for (int nn = 0; nn < 16; ++nn) {
      const int n = rs * 16 + nn;
      const float4 kk4 = *(const float4*)(kp + n * 20 + m4 * 4);
      const float4 vv4 = *(const float4*)(vS + n * 68 + eg * 4);
      const float kk[4] = {kk4.x, kk4.y, kk4.z, kk4.w};
      const float vv[4] = {vv4.x, vv4.y, vv4.z, vv4.w};
#pragma unroll
      for (int i = 0; i < 4; ++i)
#pragma unroll
        for (int j = 0; j < 4; ++j) acc2[i][j] = fmaf(kk[i], vv[j], acc2[i][j]);
      if (eg == 0) {
#pragma unroll
        for (int i = 0; i < 4; ++i) uacc[i] += kk[i];
      }
    }
  }
  {
    float* Ub = ws + OFF_U + ((size_t)bh * 272 + 256 + m4 * 4) * 64 + eg * 4;
#pragma unroll
    for (int i = 0; i < 4; ++i)
#pragma unroll
      for (int j = 0; j < 4; ++j) atomicAdd(Ub + (size_t)i * 64 + j, acc2[i][j]);
    if (eg == 0) {
#pragma unroll
      for (int i = 0; i < 4; ++i)
        atomicAdd(ws + OFF_u + (size_t)bh * 272 + 256 + m4 * 4 + i, uacc[i]);
    }
  }
#pragma unroll
  for (int o = 32; o > 0; o >>= 1) smax = fmaxf(smax, __shfl_xor(smax, o));
  if (lane == 0) redb[wv] = smax;
  __syncthreads();
  if (t == 0) {
    const float m = fmaxf(fmaxf(redb[0], redb[1]), fmaxf(redb[2], redb[3]));
    atomicMax((unsigned*)(ws + OFF_S), fenc(m));
  }
}

// --------------------------- K2: sv[e] = sum_n v ----------------------------
__global__ __launch_bounds__(256) void sv_kernel(const float* __restrict__ vg,
                                                 float* __restrict__ ws) {
  const int t = threadIdx.x;
  const int bh = blockIdx.x, nz = blockIdx.y;
  const int e = t & 63, wv = t >> 6;
  const float* vp = vg + ((size_t)bh * 4096 + (size_t)nz * 512) * 64;
  float s = 0.f;
  for (int i = 0; i < 128; ++i) s += vp[(wv * 128 + i) * 64 + e];
  atomicAdd(ws + OFF_SV + bh * 64 + e, s);
}

// --------------------------- K3: combine -> ctx_ext, Sc, Sk -----------------
__global__ __launch_bounds__(256) void combine_kernel(float* __restrict__ ws) {
  __shared__ float red[256];
  const int t = threadIdx.x;
  const int bh = blockIdx.x;
  const float S = fdec(((unsigned*)(ws + OFF_S))[0]);
  const float es = __expf(-S);
  const int e = t & 63, mr = t >> 6;
  const float svv = ws[OFF_SV + bh * 64 + e];
  float scp = 0.f;
  for (int mm = mr; mm < 272; mm += 4) {
    float val = 0.f;
    if (mm < 266)
      val = (es * ws[OFF_U + ((size_t)bh * 272 + mm) * 64 + e] + EPSV * svv) * INV_L;
    ws[OFF_CTX + ((size_t)bh * 272 + mm) * 68 + e] = val;
    scp += val;
  }
  red[t] = scp;
  __syncthreads();
  if (t < 64) ws[OFF_SC + bh * 64 + t] = red[t] + red[t + 64] + red[t + 128] + red[t + 192];
  __syncthreads();
  float skp = 0.f;
  for (int mm = t; mm < 272; mm += 256) {
    float km = 0.f;
    if (mm < 266) km = es * ws[OFF_u + (size_t)bh * 272 + mm] * INV_L + EPSV;
    float* cx = ws + OFF_CTX + ((size_t)bh * 272 + mm) * 68;
    cx[64] = km; cx[65] = 0.f; cx[66] = 0.f; cx[67] = 0.f;
    skp += km;
  }
  red[t] = skp;
  __syncthreads();
  for (int s = 128; s > 0; s >>= 1) {
    if (t < s) red[t] += red[t + s];
    __syncthreads();
  }
  if (t == 0) ws[OFF_SK + bh] = red[0];
}

// --------------------------- K4: q-pass -> out ------------------------------
__global__ __launch_bounds__(256) void pass_q(const float* __restrict__ qg,
                                              float* __restrict__ outg,
                                              const float* __restrict__ ws) {
  __shared__ __align__(16) float qT[64 * 36];   // qT[td][row], stride 36, 32 rows
  __shared__ __align__(16) float qph[32 * 276]; // qph[row][m], stride 276
  __shared__ float diag[32];
  __shared__ unsigned rmx[32];
  __shared__ float Bl[32];

  const int t = threadIdx.x;
  const int nt = blockIdx.x, bh = blockIdx.y;
  const int lane = t & 63, wv = t >> 6;
  const float* qgp = qg + ((size_t)bh * 4096 + (size_t)nt * 32) * 64;

  if (t < 32) rmx[t] = 0x007FFFFFu; // enc(-inf)

  // stage 32 rows (transposed) + diag
#pragma unroll
  for (int i = 0; i < 8; ++i) {
    const int row = i * 4 + wv;
    const float qv = qgp[row * 64 + lane];
    qT[lane * 36 + row] = qv;
    float sq = qv * qv;
#pragma unroll
    for (int o = 32; o > 0; o >>= 1) sq += __shfl_xor(sq, o);
    if (lane == 0) diag[row] = sq * DIAG_SCALE;
  }
  __syncthreads();

  // GEMM1 main: mq = lane (64 quads, m<256); rows wv*8..wv*8+7
  const int mq = t & 63;
  float a1[8][4];
#pragma unroll
  for (int i = 0; i < 8; ++i) { a1[i][0] = a1[i][1] = a1[i][2] = a1[i][3] = 0.f; }
#pragma unroll 2
  for (int td = 0; td < 64; ++td) {
    const float4 p4 = *(const float4*)(ws + OFF_PT + (size_t)td * 272 + mq * 4);
    const float pp[4] = {p4.x, p4.y, p4.z, p4.w};
    const float4 q0 = *(const float4*)(qT + td * 36 + wv * 8);
    const float4 q1 = *(const float4*)(qT + td * 36 + wv * 8 + 4);
    const float qq[8] = {q0.x, q0.y, q0.z, q0.w, q1.x, q1.y, q1.z, q1.w};
#pragma unroll
    for (int i = 0; i < 8; ++i)
#pragma unroll
      for (int j = 0; j < 4; ++j) a1[i][j] = fmaf(qq[i], pp[j], a1[i][j]);
  }
  // GEMM1 tail: m_t = 256 + (t&15), rows (t>>4)*2 + {0,1}
  float at[2] = {0.f, 0.f};
  const int mt = 256 + (t & 15);
  const int r2 = (t >> 4) * 2;
#pragma unroll 4
  for (int td = 0; td < 64; ++td) {
    const float pv = ws[OFF_PT + (size_t)td * 272 + mt];
    const float2 q2 = *(const float2*)(qT + td * 36 + r2);
    at[0] = fmaf(q2.x, pv, at[0]);
    at[1] = fmaf(q2.y, pv, at[1]);
  }
  // rowmax (raw qd): main butterfly + tail group-reduce, into LDS atomicMax
#pragma unroll
  for (int i = 0; i < 8; ++i) {
    float lm = fmaxf(fmaxf(a1[i][0], a1[i][1]), fmaxf(a1[i][2], a1[i][3]));
#pragma unroll
    for (int o = 32; o > 0; o >>= 1) lm = fmaxf(lm, __shfl_xor(lm, o));
    if (lane == i) atomicMax(&rmx[wv * 8 + i], fenc(lm));
  }
#pragma unroll
  for (int s = 0; s < 2; ++s) {
    float v = (mt < 266) ? at[s] : -INFINITY;
#pragma unroll
    for (int o = 8; o > 0; o >>= 1) v = fmaxf(v, __shfl_xor(v, o));
    if ((t & 15) == 0) atomicMax(&rmx[r2 + s], fenc(v));
  }
  // exp (unstabilized) + store qph
#pragma unroll
  for (int i = 0; i < 8; ++i) {
    const int row = wv * 8 + i;
    const float dg = diag[row];
    float4 st;
    st.x = __expf(a1[i][0] - dg);
    st.y = __expf(a1[i][1] - dg);
    st.z = __expf(a1[i][2] - dg);
    st.w = __expf(a1[i][3] - dg);
    *(float4*)(qph + row * 276 + mq * 4) = st;
  }
#pragma unroll
  for (int s = 0; s < 2; ++s) {
    const int row = r2 + s;
    qph[row * 276 + mt] = (mt < 266) ? __expf(at[s] - diag[row]) : 0.f;
  }
  __syncthreads();

  // GEMM2: A[2 rows][4 cols] + B; ctx_ext from global (L2-resident, 74KB/head)
  const int cq = t & 15, rg2 = t >> 4;
  const float* ctxg = ws + OFF_CTX + (size_t)bh * 272 * 68;
  float acc[2][4] = {{0, 0, 0, 0}, {0, 0, 0, 0}};
  float accB[2] = {0.f, 0.f};
  for (int m4i = 0; m4i < 68; ++m4i) {
    const int mm = m4i * 4;
    const float4 qa4 = *(const float4*)(qph + (rg2 * 2) * 276 + mm);
    const float4 qb4 = *(const float4*)(qph + (rg2 * 2 + 1) * 276 + mm);
    const float qa[4] = {qa4.x, qa4.y, qa4.z, qa4.w};
    const float qb[4] = {qb4.x, qb4.y, qb4.z, qb4.w};
#pragma unroll
    for (int u4 = 0; u4 < 4; ++u4) {
      const float4 c4 = *(const float4*)(ctxg + (size_t)(mm + u4) * 68 + cq * 4);
      acc[0][0] = fmaf(qa[u4], c4.x, acc[0][0]);
      acc[0][1] = fmaf(qa[u4], c4.y, acc[0][1]);
      acc[0][2] = fmaf(qa[u4], c4.z, acc[0][2]);
      acc[0][3] = fmaf(qa[u4], c4.w, acc[0][3]);
      acc[1][0] = fmaf(qb[u4], c4.x, acc[1][0]);
      acc[1][1] = fmaf(qb[u4], c4.y, acc[1][1]);
      acc[1][2] = fmaf(qb[u4], c4.z, acc[1][2]);
      acc[1][3] = fmaf(qb[u4], c4.w, acc[1][3]);
      if (cq == 0) {
        const float cb = ctxg[(size_t)(mm + u4) * 68 + 64];
        accB[0] = fmaf(qa[u4], cb, accB[0]);
        accB[1] = fmaf(qb[u4], cb, accB[1]);
      }
    }
  }
  if (cq == 0) {
    Bl[rg2 * 2] = accB[0];
    Bl[rg2 * 2 + 1] = accB[1];
  }
  __syncthreads();

  const float4 sc4 = *(const float4*)(ws + OFF_SC + bh * 64 + cq * 4);
  const float skv = ws[OFF_SK + bh];
  float* op = outg + ((size_t)bh * 4096 + (size_t)nt * 32) * 64;
#pragma unroll
  for (int i = 0; i < 2; ++i) {
    const int row = rg2 * 2 + i;
    const float rm = fdec(rmx[row]);
    const float tt = EPSV * __expf(rm);
    const float inv = 1.0f / (Bl[row] + tt * skv);
    float4 o;
    o.x = (acc[i][0] + tt * sc4.x) * inv;
    o.y = (acc[i][1] + tt * sc4.y) * inv;
    o.z = (acc[i][2] + tt * sc4.z) * inv;
    o.w = (acc[i][3] + tt * sc4.w) * inv;
    *(float4*)(op + row * 64 + cq * 4) = o;
  }
}

// --------------------------- launch -----------------------------------------
extern "C" void kernel_launch(void* const* d_in, const int* in_sizes, int n_in,
                              void* d_out, int out_size, void* d_ws, size_t ws_size,
                              hipStream_t stream) {
  (void)in_sizes; (void)n_in; (void)out_size; (void)ws_size;
  const float* q = (const float*)d_in[0];
  const float* k = (const float*)d_in[1];
  const float* v = (const float*)d_in[2];
  const float* P = (const float*)d_in[3];
  float* out = (float*)d_out;
  float* ws = (float*)d_ws;

  hipMemsetAsync(d_ws, 0, WS_FLOATS * sizeof(float), stream);
  setup_kernel<<<68, 256, 0, stream>>>(P, ws);
  pass_k_main<<<dim3(4, 32, 4), 256, 0, stream>>>(k, v, ws);
  pass_k_tail<<<dim3(32, 4), 256, 0, stream>>>(k, v, ws);
  sv_kernel<<<dim3(32, 8), 256, 0, stream>>>(v, ws);
  combine_kernel<<<32, 256, 0, stream>>>(ws);
  pass_q<<<dim3(128, 32), 256, 0, stream>>>(q, out, ws);
}